// Round 6
// baseline (2362.983 us; speedup 1.0000x reference)
//
#include <hip/hip_runtime.h>
#include <hip/hip_bf16.h>

#define BB 4096
#define DD 64
#define HH 512

// fp32 inputs, fp32 output (reference computes in float32 throughout).
// ws layout: X = h1/g1 (B*H f32), Y = h2/g2 (B*H f32). ws_size >= 16MB (proven R5).
// Q_diag is stashed in out[:, 64:] (f32) by k3(act=1), consumed+overwritten by k4.

// k1: X[b,h] = tanh(mu @ W^T + bias), K=64. mu = states[:, :64] (f32 B x 128).
__global__ __launch_bounds__(256) void k1_stage1(
    const float* __restrict__ states,
    const float* __restrict__ W, const float* __restrict__ bias,
    float* __restrict__ out) {
  __shared__ __align__(16) float aT[64 * 68];
  __shared__ __align__(16) float wT[64 * 68];
  const int bt = blockIdx.x * 64;
  const int ht = blockIdx.y * 64;
  const int t = threadIdx.x;

#pragma unroll
  for (int i = 0; i < 16; ++i) {
    int idx = t + i * 256;
    int r = idx >> 6, k = idx & 63;
    aT[k * 68 + r] = states[(size_t)(bt + r) * 128 + k];
    wT[k * 68 + r] = W[(size_t)(ht + r) * 64 + k];
  }
  __syncthreads();

  const int bi = (t & 15) * 4, hj = (t >> 4) * 4;
  float acc[4][4] = {};
#pragma unroll
  for (int k = 0; k < 64; ++k) {
    float4 av = *(const float4*)(aT + k * 68 + bi);
    float4 bv = *(const float4*)(wT + k * 68 + hj);
    float ar[4] = {av.x, av.y, av.z, av.w};
    float br[4] = {bv.x, bv.y, bv.z, bv.w};
#pragma unroll
    for (int i = 0; i < 4; ++i)
#pragma unroll
      for (int j = 0; j < 4; ++j) acc[i][j] += ar[i] * br[j];
  }
#pragma unroll
  for (int j = 0; j < 4; ++j) {
    float bsv = bias[ht + hj + j];
#pragma unroll
    for (int i = 0; i < 4; ++i)
      out[(size_t)(bt + bi + i) * HH + ht + hj + j] = tanhf(acc[i][j] + bsv);
  }
}

// k2: Y[b,h] = tanh(A @ W^T + bias), K=512.
__global__ __launch_bounds__(256) void k2_stage2(
    const float* __restrict__ A,
    const float* __restrict__ W, const float* __restrict__ bias,
    float* __restrict__ out) {
  __shared__ __align__(16) float aT[32 * 68];
  __shared__ __align__(16) float wT[32 * 68];
  const int bt = blockIdx.x * 64;
  const int ht = blockIdx.y * 64;
  const int t = threadIdx.x;
  const int bi = (t & 15) * 4, hj = (t >> 4) * 4;
  float acc[4][4] = {};

  for (int kc = 0; kc < HH; kc += 32) {
#pragma unroll
    for (int i = 0; i < 8; ++i) {
      int idx = t + i * 256;
      int r = idx >> 5, k = idx & 31;
      aT[k * 68 + r] = A[(size_t)(bt + r) * HH + kc + k];
      wT[k * 68 + r] = W[(size_t)(ht + r) * HH + kc + k];
    }
    __syncthreads();
#pragma unroll
    for (int k = 0; k < 32; ++k) {
      float4 av = *(const float4*)(aT + k * 68 + bi);
      float4 bv = *(const float4*)(wT + k * 68 + hj);
      float ar[4] = {av.x, av.y, av.z, av.w};
      float br[4] = {bv.x, bv.y, bv.z, bv.w};
#pragma unroll
      for (int i = 0; i < 4; ++i)
#pragma unroll
        for (int j = 0; j < 4; ++j) acc[i][j] += ar[i] * br[j];
    }
    __syncthreads();
  }
#pragma unroll
  for (int j = 0; j < 4; ++j) {
    float bsv = bias[ht + hj + j];
#pragma unroll
    for (int i = 0; i < 4; ++i)
      out[(size_t)(bt + bi + i) * HH + ht + hj + j] = tanhf(acc[i][j] + bsv);
  }
}

// k3: tmp = A @ W^T + bias (W f32 64 x 512).
//     act==0: out[b*128 + colOff + o] = tmp
//     act==1: out[b*128 + colOff + o] = softplus(tmp)   (f32 Q_diag stash)
__global__ __launch_bounds__(256) void k3_stage3(
    const float* __restrict__ A,
    const float* __restrict__ W, const float* __restrict__ bias,
    float* __restrict__ out, int colOff, int act) {
  __shared__ __align__(16) float aT[32 * 68];
  __shared__ __align__(16) float wT[32 * 68];
  const int bt = blockIdx.x * 64;
  const int t = threadIdx.x;
  const int bi = (t & 15) * 4, oj = (t >> 4) * 4;
  float acc[4][4] = {};

  for (int kc = 0; kc < HH; kc += 32) {
#pragma unroll
    for (int i = 0; i < 8; ++i) {
      int idx = t + i * 256;
      int r = idx >> 5, k = idx & 31;
      aT[k * 68 + r] = A[(size_t)(bt + r) * HH + kc + k];
      wT[k * 68 + r] = W[(size_t)r * HH + kc + k];
    }
    __syncthreads();
#pragma unroll
    for (int k = 0; k < 32; ++k) {
      float4 av = *(const float4*)(aT + k * 68 + bi);
      float4 bv = *(const float4*)(wT + k * 68 + oj);
      float ar[4] = {av.x, av.y, av.z, av.w};
      float br[4] = {bv.x, bv.y, bv.z, bv.w};
#pragma unroll
      for (int i = 0; i < 4; ++i)
#pragma unroll
        for (int j = 0; j < 4; ++j) acc[i][j] += ar[i] * br[j];
    }
    __syncthreads();
  }
#pragma unroll
  for (int j = 0; j < 4; ++j) {
    float bsv = bias[oj + j];
#pragma unroll
    for (int i = 0; i < 4; ++i) {
      float v = acc[i][j] + bsv;
      if (act) v = fmaxf(v, 0.0f) + log1pf(expf(-fabsf(v)));
      out[(size_t)(bt + bi + i) * 128 + colOff + oj + j] = v;
    }
  }
}

// k4: J_diag[b,d] = sum_h d2[b,h]*W3[d,h] * (sum_k d1[b,k]*W2[h,k]*W1[k,d])
//     out[b,64+d] = 2*J_diag*sigma[b,d] + Qd(stashed f32)
__global__ __launch_bounds__(256) void k4_jdiag(
    const float* __restrict__ h1, const float* __restrict__ h2,
    const float* __restrict__ W1, const float* __restrict__ W2,
    const float* __restrict__ W3, const float* __restrict__ states,
    float* __restrict__ out) {
  __shared__ __align__(16) float aT[32 * 68];
  __shared__ __align__(16) float mT[32 * 68];
  __shared__ float red[64 * 17];
  const int bt = blockIdx.x * 64;
  const int d = blockIdx.y;
  const int t = threadIdx.x;
  const int bi = (t & 15) * 4, hj = (t >> 4) * 4;
  float s[4] = {0.f, 0.f, 0.f, 0.f};

  for (int ht = 0; ht < HH; ht += 64) {
    float acc[4][4] = {};
    for (int kc = 0; kc < HH; kc += 32) {
#pragma unroll
      for (int i = 0; i < 8; ++i) {
        int idx = t + i * 256;
        int r = idx >> 5, k = idx & 31;
        int kg = kc + k;
        float hv = h1[(size_t)(bt + r) * HH + kg];
        aT[k * 68 + r] = 1.0f - hv * hv;
        mT[k * 68 + r] = W2[(size_t)(ht + r) * HH + kg] * W1[(size_t)kg * DD + d];
      }
      __syncthreads();
#pragma unroll
      for (int k = 0; k < 32; ++k) {
        float4 av = *(const float4*)(aT + k * 68 + bi);
        float4 bv = *(const float4*)(mT + k * 68 + hj);
        float ar[4] = {av.x, av.y, av.z, av.w};
        float br[4] = {bv.x, bv.y, bv.z, bv.w};
#pragma unroll
        for (int i = 0; i < 4; ++i)
#pragma unroll
          for (int j = 0; j < 4; ++j) acc[i][j] += ar[i] * br[j];
      }
      __syncthreads();
    }
#pragma unroll
    for (int j = 0; j < 4; ++j) {
      int hg = ht + hj + j;
      float w3 = W3[(size_t)d * HH + hg];
#pragma unroll
      for (int i = 0; i < 4; ++i) {
        float h2v = h2[(size_t)(bt + bi + i) * HH + hg];
        s[i] += acc[i][j] * (1.0f - h2v * h2v) * w3;
      }
    }
  }
#pragma unroll
  for (int i = 0; i < 4; ++i) red[(bi + i) * 17 + (t >> 4)] = s[i];
  __syncthreads();
  if (t < 64) {
    float sum = 0.f;
#pragma unroll
    for (int g = 0; g < 16; ++g) sum += red[t * 17 + g];
    int bg = bt + t;
    float sig = states[(size_t)bg * 128 + 64 + d];
    float qd = out[(size_t)bg * 128 + 64 + d];
    out[(size_t)bg * 128 + 64 + d] = 2.0f * sum * sig + qd;
  }
}

extern "C" void kernel_launch(void* const* d_in, const int* in_sizes, int n_in,
                              void* d_out, int out_size, void* d_ws, size_t ws_size,
                              hipStream_t stream) {
  // inputs: 0:t 1:states 2:W1 3:b1 4:W2 5:b2 6:W3 7:b3 8:V1 9:c1 10:V2 11:c2 12:V3 13:c3
  const float* states = (const float*)d_in[1];
  const float* W1 = (const float*)d_in[2];
  const float* b1 = (const float*)d_in[3];
  const float* W2 = (const float*)d_in[4];
  const float* b2 = (const float*)d_in[5];
  const float* W3 = (const float*)d_in[6];
  const float* b3 = (const float*)d_in[7];
  const float* V1 = (const float*)d_in[8];
  const float* c1 = (const float*)d_in[9];
  const float* V2 = (const float*)d_in[10];
  const float* c2 = (const float*)d_in[11];
  const float* V3 = (const float*)d_in[12];
  const float* c3 = (const float*)d_in[13];
  float* out = (float*)d_out;

  float* X = (float*)d_ws;           // B*H f32
  float* Y = X + (size_t)BB * HH;    // B*H f32   (ws_size >= 16MB, proven R5)

  // Q path; stash Q_diag (softplus, f32) into out[:, 64:]
  k1_stage1<<<dim3(64, 8), 256, 0, stream>>>(states, V1, c1, X);      // g1
  k2_stage2<<<dim3(64, 8), 256, 0, stream>>>(X, V2, c2, Y);           // g2
  k3_stage3<<<dim3(64), 256, 0, stream>>>(Y, V3, c3, out, 64, 1);     // Qd
  // h path
  k1_stage1<<<dim3(64, 8), 256, 0, stream>>>(states, W1, b1, X);      // h1
  k2_stage2<<<dim3(64, 8), 256, 0, stream>>>(X, W2, b2, Y);           // h2
  k3_stage3<<<dim3(64), 256, 0, stream>>>(Y, W3, b3, out, 0, 0);      // mu_drift
  // J_diag + final sigma_drift
  k4_jdiag<<<dim3(64, 64), 256, 0, stream>>>(X, Y, W1, W2, W3, states, out);
}

// Round 7
// 857.428 us; speedup vs baseline: 2.7559x; 2.7559x over previous
//
#include <hip/hip_runtime.h>
#include <hip/hip_bf16.h>

#define BB 4096
#define DD 64
#define HH 512

typedef __attribute__((ext_vector_type(8))) short bf16x8;
typedef __attribute__((ext_vector_type(4))) float f32x4;

// fp32 inputs, fp32 output. ws: X = h1/g1, Y = h2/g2 (B*H f32 each).
// Q_diag stashed f32 in out[:, 64:] by k3(act=1), consumed+overwritten by k4.

// ---------------------------------------------------------------------------
// k1: X[b,h] = tanh(mu @ W^T + bias), K=64.
// ---------------------------------------------------------------------------
__global__ __launch_bounds__(256) void k1_stage1(
    const float* __restrict__ states,
    const float* __restrict__ W, const float* __restrict__ bias,
    float* __restrict__ out) {
  __shared__ __align__(16) float aT[64 * 68];
  __shared__ __align__(16) float wT[64 * 68];
  const int bt = blockIdx.x * 64;
  const int ht = blockIdx.y * 64;
  const int t = threadIdx.x;

#pragma unroll
  for (int i = 0; i < 16; ++i) {
    int idx = t + i * 256;
    int r = idx >> 6, k = idx & 63;
    aT[k * 68 + r] = states[(size_t)(bt + r) * 128 + k];
    wT[k * 68 + r] = W[(size_t)(ht + r) * 64 + k];
  }
  __syncthreads();

  const int bi = (t & 15) * 4, hj = (t >> 4) * 4;
  float acc[4][4] = {};
#pragma unroll
  for (int k = 0; k < 64; ++k) {
    float4 av = *(const float4*)(aT + k * 68 + bi);
    float4 bv = *(const float4*)(wT + k * 68 + hj);
    float ar[4] = {av.x, av.y, av.z, av.w};
    float br[4] = {bv.x, bv.y, bv.z, bv.w};
#pragma unroll
    for (int i = 0; i < 4; ++i)
#pragma unroll
      for (int j = 0; j < 4; ++j) acc[i][j] += ar[i] * br[j];
  }
#pragma unroll
  for (int j = 0; j < 4; ++j) {
    float bsv = bias[ht + hj + j];
#pragma unroll
    for (int i = 0; i < 4; ++i)
      out[(size_t)(bt + bi + i) * HH + ht + hj + j] = tanhf(acc[i][j] + bsv);
  }
}

// ---------------------------------------------------------------------------
// k2: Y[b,h] = tanh(A @ W^T + bias), K=512.
// ---------------------------------------------------------------------------
__global__ __launch_bounds__(256) void k2_stage2(
    const float* __restrict__ A,
    const float* __restrict__ W, const float* __restrict__ bias,
    float* __restrict__ out) {
  __shared__ __align__(16) float aT[32 * 68];
  __shared__ __align__(16) float wT[32 * 68];
  const int bt = blockIdx.x * 64;
  const int ht = blockIdx.y * 64;
  const int t = threadIdx.x;
  const int bi = (t & 15) * 4, hj = (t >> 4) * 4;
  float acc[4][4] = {};

  for (int kc = 0; kc < HH; kc += 32) {
#pragma unroll
    for (int i = 0; i < 8; ++i) {
      int idx = t + i * 256;
      int r = idx >> 5, k = idx & 31;
      aT[k * 68 + r] = A[(size_t)(bt + r) * HH + kc + k];
      wT[k * 68 + r] = W[(size_t)(ht + r) * HH + kc + k];
    }
    __syncthreads();
#pragma unroll
    for (int k = 0; k < 32; ++k) {
      float4 av = *(const float4*)(aT + k * 68 + bi);
      float4 bv = *(const float4*)(wT + k * 68 + hj);
      float ar[4] = {av.x, av.y, av.z, av.w};
      float br[4] = {bv.x, bv.y, bv.z, bv.w};
#pragma unroll
      for (int i = 0; i < 4; ++i)
#pragma unroll
        for (int j = 0; j < 4; ++j) acc[i][j] += ar[i] * br[j];
    }
    __syncthreads();
  }
#pragma unroll
  for (int j = 0; j < 4; ++j) {
    float bsv = bias[ht + hj + j];
#pragma unroll
    for (int i = 0; i < 4; ++i)
      out[(size_t)(bt + bi + i) * HH + ht + hj + j] = tanhf(acc[i][j] + bsv);
  }
}

// ---------------------------------------------------------------------------
// k3: tmp = A @ W^T + bias (W 64 x 512).  act? softplus.
// ---------------------------------------------------------------------------
__global__ __launch_bounds__(256) void k3_stage3(
    const float* __restrict__ A,
    const float* __restrict__ W, const float* __restrict__ bias,
    float* __restrict__ out, int colOff, int act) {
  __shared__ __align__(16) float aT[32 * 68];
  __shared__ __align__(16) float wT[32 * 68];
  const int bt = blockIdx.x * 64;
  const int t = threadIdx.x;
  const int bi = (t & 15) * 4, oj = (t >> 4) * 4;
  float acc[4][4] = {};

  for (int kc = 0; kc < HH; kc += 32) {
#pragma unroll
    for (int i = 0; i < 8; ++i) {
      int idx = t + i * 256;
      int r = idx >> 5, k = idx & 31;
      aT[k * 68 + r] = A[(size_t)(bt + r) * HH + kc + k];
      wT[k * 68 + r] = W[(size_t)r * HH + kc + k];
    }
    __syncthreads();
#pragma unroll
    for (int k = 0; k < 32; ++k) {
      float4 av = *(const float4*)(aT + k * 68 + bi);
      float4 bv = *(const float4*)(wT + k * 68 + oj);
      float ar[4] = {av.x, av.y, av.z, av.w};
      float br[4] = {bv.x, bv.y, bv.z, bv.w};
#pragma unroll
      for (int i = 0; i < 4; ++i)
#pragma unroll
        for (int j = 0; j < 4; ++j) acc[i][j] += ar[i] * br[j];
    }
    __syncthreads();
  }
#pragma unroll
  for (int j = 0; j < 4; ++j) {
    float bsv = bias[oj + j];
#pragma unroll
    for (int i = 0; i < 4; ++i) {
      float v = acc[i][j] + bsv;
      if (act) v = fmaxf(v, 0.0f) + log1pf(expf(-fabsf(v)));
      out[(size_t)(bt + bi + i) * 128 + colOff + oj + j] = v;
    }
  }
}

// ---------------------------------------------------------------------------
// k4 (MFMA): J_diag[b,d] = sum_h E[b,h] * C_d[b,h],
//   C_d = (d1 o W1[:,d]) @ W2^T (fp32 acc, bf16 inputs), E = (1-h2^2)*W3[d,:]
// grid (B/64, 64 d), block 256 (4 waves). Per wave: 16 h-cols x 64 b-rows.
// LDS: A_d 64x520 bf16 (66.5K), Btile 64x520 bf16 (66.5K), E 64x68 bf16,
//      w1col/w3row f32, red 4x64 f32.  Total ~147 KB -> 1 block/CU.
// ---------------------------------------------------------------------------
__global__ __launch_bounds__(256) void k4_mfma(
    const float* __restrict__ X, const float* __restrict__ Y,
    const float* __restrict__ W1, const float* __restrict__ W2,
    const float* __restrict__ W3, const float* __restrict__ states,
    float* __restrict__ out) {
  __shared__ __align__(16) __hip_bfloat16 Ald[64 * 520];
  __shared__ __align__(16) __hip_bfloat16 Btile[64 * 520];
  __shared__ __align__(16) __hip_bfloat16 Etile[64 * 68];
  __shared__ __align__(16) float w1col[512];
  __shared__ __align__(16) float w3row[512];
  __shared__ float red[4 * 64];

  const int bt = blockIdx.x * 64;
  const int d = blockIdx.y;
  const int t = threadIdx.x;
  const int lane = t & 63;
  const int w = t >> 6;          // wave id 0..3
  const int c = lane & 15;       // col lane
  const int q = lane >> 4;       // quad

  // stage W1 column d and W3 row d
#pragma unroll
  for (int i = 0; i < 2; ++i) {
    int k = t + i * 256;
    w1col[k] = W1[(size_t)k * DD + d];
    w3row[k] = W3[(size_t)d * HH + k];
  }
  __syncthreads();

  // build A_d = bf16((1 - X^2) * w1col), 64 x 512, row stride 520
#pragma unroll
  for (int i = 0; i < 32; ++i) {
    int g = t + i * 256;               // float4 group
    int b = g >> 7, c4 = (g & 127) * 4;
    float4 xv = *(const float4*)(X + (size_t)(bt + b) * HH + c4);
    float4 wv = *(const float4*)(w1col + c4);
    union { __hip_bfloat16 h[4]; uint2 u; } p;
    p.h[0] = __float2bfloat16((1.f - xv.x * xv.x) * wv.x);
    p.h[1] = __float2bfloat16((1.f - xv.y * xv.y) * wv.y);
    p.h[2] = __float2bfloat16((1.f - xv.z * xv.z) * wv.z);
    p.h[3] = __float2bfloat16((1.f - xv.w * xv.w) * wv.w);
    *(uint2*)(Ald + b * 520 + c4) = p.u;
  }

  float jp[4][4];   // per-lane partial J: [m-tile][reg]
#pragma unroll
  for (int i = 0; i < 4; ++i)
#pragma unroll
    for (int j = 0; j < 4; ++j) jp[i][j] = 0.f;

  for (int ht = 0; ht < 8; ++ht) {
    const int hg0 = ht * 64;
    __syncthreads();   // prev readers of Btile/Etile done (also fences A build)
    // stage W2 h-rows (64 x 512) as bf16
#pragma unroll
    for (int i = 0; i < 32; ++i) {
      int g = t + i * 256;
      int r = g >> 7, c4 = (g & 127) * 4;
      float4 wv = *(const float4*)(W2 + (size_t)(hg0 + r) * HH + c4);
      union { __hip_bfloat16 h[4]; uint2 u; } p;
      p.h[0] = __float2bfloat16(wv.x);
      p.h[1] = __float2bfloat16(wv.y);
      p.h[2] = __float2bfloat16(wv.z);
      p.h[3] = __float2bfloat16(wv.w);
      *(uint2*)(Btile + r * 520 + c4) = p.u;
    }
    // stage E = (1 - Y^2) * w3row for this h-tile (64b x 64h), stride 68
#pragma unroll
    for (int i = 0; i < 4; ++i) {
      int g = t + i * 256;
      int br = g >> 4, hc4 = (g & 15) * 4;
      float4 yv = *(const float4*)(Y + (size_t)(bt + br) * HH + hg0 + hc4);
      union { __hip_bfloat16 h[4]; uint2 u; } p;
      p.h[0] = __float2bfloat16((1.f - yv.x * yv.x) * w3row[hg0 + hc4 + 0]);
      p.h[1] = __float2bfloat16((1.f - yv.y * yv.y) * w3row[hg0 + hc4 + 1]);
      p.h[2] = __float2bfloat16((1.f - yv.z * yv.z) * w3row[hg0 + hc4 + 2]);
      p.h[3] = __float2bfloat16((1.f - yv.w * yv.w) * w3row[hg0 + hc4 + 3]);
      *(uint2*)(Etile + br * 68 + hc4) = p.u;
    }
    __syncthreads();

    // MFMA: C(64b x 16h per wave) = A_d @ Btile^T, K = 512
    f32x4 acc[4] = {f32x4{0,0,0,0}, f32x4{0,0,0,0}, f32x4{0,0,0,0}, f32x4{0,0,0,0}};
#pragma unroll
    for (int s = 0; s < 16; ++s) {
      uint4 braw = *(const uint4*)(Btile + (w * 16 + c) * 520 + s * 32 + q * 8);
      bf16x8 bf = __builtin_bit_cast(bf16x8, braw);
#pragma unroll
      for (int mt = 0; mt < 4; ++mt) {
        uint4 araw = *(const uint4*)(Ald + (mt * 16 + c) * 520 + s * 32 + q * 8);
        bf16x8 af = __builtin_bit_cast(bf16x8, araw);
        acc[mt] = __builtin_amdgcn_mfma_f32_16x16x32_bf16(af, bf, acc[mt], 0, 0, 0);
      }
    }
    // epilogue: jp[b-row] += C * E  (C row = mt*16 + q*4 + reg, col = w*16+c)
#pragma unroll
    for (int mt = 0; mt < 4; ++mt) {
#pragma unroll
      for (int r = 0; r < 4; ++r) {
        int row = mt * 16 + q * 4 + r;
        float e = __bfloat162float(Etile[row * 68 + w * 16 + c]);
        jp[mt][r] += acc[mt][r] * e;
      }
    }
  }

  // reduce over col-lanes (xor 1,2,4,8 keeps q), then across waves via LDS
#pragma unroll
  for (int mt = 0; mt < 4; ++mt)
#pragma unroll
    for (int r = 0; r < 4; ++r) {
      float v = jp[mt][r];
      v += __shfl_xor(v, 1);
      v += __shfl_xor(v, 2);
      v += __shfl_xor(v, 4);
      v += __shfl_xor(v, 8);
      jp[mt][r] = v;
    }
  if (c == 0) {
#pragma unroll
    for (int mt = 0; mt < 4; ++mt)
#pragma unroll
      for (int r = 0; r < 4; ++r)
        red[w * 64 + mt * 16 + q * 4 + r] = jp[mt][r];
  }
  __syncthreads();
  if (t < 64) {
    float J = red[t] + red[64 + t] + red[128 + t] + red[192 + t];
    int bg = bt + t;
    float sig = states[(size_t)bg * 128 + 64 + d];
    float qd = out[(size_t)bg * 128 + 64 + d];
    out[(size_t)bg * 128 + 64 + d] = 2.0f * J * sig + qd;
  }
}

extern "C" void kernel_launch(void* const* d_in, const int* in_sizes, int n_in,
                              void* d_out, int out_size, void* d_ws, size_t ws_size,
                              hipStream_t stream) {
  // inputs: 0:t 1:states 2:W1 3:b1 4:W2 5:b2 6:W3 7:b3 8:V1 9:c1 10:V2 11:c2 12:V3 13:c3
  const float* states = (const float*)d_in[1];
  const float* W1 = (const float*)d_in[2];
  const float* b1 = (const float*)d_in[3];
  const float* W2 = (const float*)d_in[4];
  const float* b2 = (const float*)d_in[5];
  const float* W3 = (const float*)d_in[6];
  const float* b3 = (const float*)d_in[7];
  const float* V1 = (const float*)d_in[8];
  const float* c1 = (const float*)d_in[9];
  const float* V2 = (const float*)d_in[10];
  const float* c2 = (const float*)d_in[11];
  const float* V3 = (const float*)d_in[12];
  const float* c3 = (const float*)d_in[13];
  float* out = (float*)d_out;

  float* X = (float*)d_ws;           // B*H f32
  float* Y = X + (size_t)BB * HH;    // B*H f32

  // Q path; stash Q_diag (softplus, f32) into out[:, 64:]
  k1_stage1<<<dim3(64, 8), 256, 0, stream>>>(states, V1, c1, X);      // g1
  k2_stage2<<<dim3(64, 8), 256, 0, stream>>>(X, V2, c2, Y);           // g2
  k3_stage3<<<dim3(64), 256, 0, stream>>>(Y, V3, c3, out, 64, 1);     // Qd
  // h path
  k1_stage1<<<dim3(64, 8), 256, 0, stream>>>(states, W1, b1, X);      // h1
  k2_stage2<<<dim3(64, 8), 256, 0, stream>>>(X, W2, b2, Y);           // h2
  k3_stage3<<<dim3(64), 256, 0, stream>>>(Y, W3, b3, out, 0, 0);      // mu_drift
  // J_diag + final sigma_drift  (bf16 MFMA)
  k4_mfma<<<dim3(64, 64), 256, 0, stream>>>(X, Y, W1, W2, W3, states, out);
}

// Round 8
// 689.866 us; speedup vs baseline: 3.4253x; 1.2429x over previous
//
#include <hip/hip_runtime.h>
#include <hip/hip_bf16.h>

#define BB 4096
#define DD 64
#define HH 512

typedef __hip_bfloat16 bf16;
typedef __attribute__((ext_vector_type(8))) short bf16x8;
typedef __attribute__((ext_vector_type(4))) float f32x4;

__device__ __forceinline__ float bf2f(bf16 x) { return __bfloat162float(x); }
__device__ __forceinline__ float u16tof(unsigned short u) {
  union { unsigned int i; float f; } v; v.i = ((unsigned int)u) << 16; return v.f;
}

// ws: Xbf (B*H bf16) | Ybf (B*H bf16) | W2bf (H*H bf16)  = 8.5 MB total.
// Q_diag stashed f32 in out[:, 64:] by k3(act=1), consumed+overwritten by k4.

// ---------------------------------------------------------------------------
// w2cvt: W2bf = bf16(W2)   (pure elementwise)
// ---------------------------------------------------------------------------
__global__ __launch_bounds__(256) void w2cvt(const float* __restrict__ W2,
                                             bf16* __restrict__ W2bf) {
  int i = (blockIdx.x * 256 + threadIdx.x) * 4;
  float4 v = *(const float4*)(W2 + i);
  bf16 o[4] = {__float2bfloat16(v.x), __float2bfloat16(v.y),
               __float2bfloat16(v.z), __float2bfloat16(v.w)};
  *(uint2*)(W2bf + i) = *(uint2*)o;
}

// ---------------------------------------------------------------------------
// k1: Xbf[b,h] = bf16(tanh(mu @ W^T + bias)), K=64.
// ---------------------------------------------------------------------------
__global__ __launch_bounds__(256) void k1_stage1(
    const float* __restrict__ states,
    const float* __restrict__ W, const float* __restrict__ bias,
    bf16* __restrict__ out) {
  __shared__ __align__(16) float aT[64 * 68];
  __shared__ __align__(16) float wT[64 * 68];
  const int bt = blockIdx.x * 64;
  const int ht = blockIdx.y * 64;
  const int t = threadIdx.x;

#pragma unroll
  for (int i = 0; i < 16; ++i) {
    int idx = t + i * 256;
    int r = idx >> 6, k = idx & 63;
    aT[k * 68 + r] = states[(size_t)(bt + r) * 128 + k];
    wT[k * 68 + r] = W[(size_t)(ht + r) * 64 + k];
  }
  __syncthreads();

  const int bi = (t & 15) * 4, hj = (t >> 4) * 4;
  float acc[4][4] = {};
#pragma unroll
  for (int k = 0; k < 64; ++k) {
    float4 av = *(const float4*)(aT + k * 68 + bi);
    float4 bv = *(const float4*)(wT + k * 68 + hj);
    float ar[4] = {av.x, av.y, av.z, av.w};
    float br[4] = {bv.x, bv.y, bv.z, bv.w};
#pragma unroll
    for (int i = 0; i < 4; ++i)
#pragma unroll
      for (int j = 0; j < 4; ++j) acc[i][j] += ar[i] * br[j];
  }
#pragma unroll
  for (int j = 0; j < 4; ++j) {
    float bsv = bias[ht + hj + j];
#pragma unroll
    for (int i = 0; i < 4; ++i)
      out[(size_t)(bt + bi + i) * HH + ht + hj + j] =
          __float2bfloat16(tanhf(acc[i][j] + bsv));
  }
}

// ---------------------------------------------------------------------------
// k2: Ybf[b,h] = bf16(tanh(A @ W^T + bias)), K=512, A bf16.
// ---------------------------------------------------------------------------
__global__ __launch_bounds__(256) void k2_stage2(
    const bf16* __restrict__ A,
    const float* __restrict__ W, const float* __restrict__ bias,
    bf16* __restrict__ out) {
  __shared__ __align__(16) float aT[32 * 68];
  __shared__ __align__(16) float wT[32 * 68];
  const int bt = blockIdx.x * 64;
  const int ht = blockIdx.y * 64;
  const int t = threadIdx.x;
  const int bi = (t & 15) * 4, hj = (t >> 4) * 4;
  float acc[4][4] = {};

  for (int kc = 0; kc < HH; kc += 32) {
#pragma unroll
    for (int i = 0; i < 8; ++i) {
      int idx = t + i * 256;
      int r = idx >> 5, k = idx & 31;
      aT[k * 68 + r] = bf2f(A[(size_t)(bt + r) * HH + kc + k]);
      wT[k * 68 + r] = W[(size_t)(ht + r) * HH + kc + k];
    }
    __syncthreads();
#pragma unroll
    for (int k = 0; k < 32; ++k) {
      float4 av = *(const float4*)(aT + k * 68 + bi);
      float4 bv = *(const float4*)(wT + k * 68 + hj);
      float ar[4] = {av.x, av.y, av.z, av.w};
      float br[4] = {bv.x, bv.y, bv.z, bv.w};
#pragma unroll
      for (int i = 0; i < 4; ++i)
#pragma unroll
        for (int j = 0; j < 4; ++j) acc[i][j] += ar[i] * br[j];
    }
    __syncthreads();
  }
#pragma unroll
  for (int j = 0; j < 4; ++j) {
    float bsv = bias[ht + hj + j];
#pragma unroll
    for (int i = 0; i < 4; ++i)
      out[(size_t)(bt + bi + i) * HH + ht + hj + j] =
          __float2bfloat16(tanhf(acc[i][j] + bsv));
  }
}

// ---------------------------------------------------------------------------
// k3: tmp = A @ W^T + bias (A bf16, W f32 64 x 512). act? softplus. out f32.
// ---------------------------------------------------------------------------
__global__ __launch_bounds__(256) void k3_stage3(
    const bf16* __restrict__ A,
    const float* __restrict__ W, const float* __restrict__ bias,
    float* __restrict__ out, int colOff, int act) {
  __shared__ __align__(16) float aT[32 * 68];
  __shared__ __align__(16) float wT[32 * 68];
  const int bt = blockIdx.x * 64;
  const int t = threadIdx.x;
  const int bi = (t & 15) * 4, oj = (t >> 4) * 4;
  float acc[4][4] = {};

  for (int kc = 0; kc < HH; kc += 32) {
#pragma unroll
    for (int i = 0; i < 8; ++i) {
      int idx = t + i * 256;
      int r = idx >> 5, k = idx & 31;
      aT[k * 68 + r] = bf2f(A[(size_t)(bt + r) * HH + kc + k]);
      wT[k * 68 + r] = W[(size_t)r * HH + kc + k];
    }
    __syncthreads();
#pragma unroll
    for (int k = 0; k < 32; ++k) {
      float4 av = *(const float4*)(aT + k * 68 + bi);
      float4 bv = *(const float4*)(wT + k * 68 + oj);
      float ar[4] = {av.x, av.y, av.z, av.w};
      float br[4] = {bv.x, bv.y, bv.z, bv.w};
#pragma unroll
      for (int i = 0; i < 4; ++i)
#pragma unroll
        for (int j = 0; j < 4; ++j) acc[i][j] += ar[i] * br[j];
    }
    __syncthreads();
  }
#pragma unroll
  for (int j = 0; j < 4; ++j) {
    float bsv = bias[oj + j];
#pragma unroll
    for (int i = 0; i < 4; ++i) {
      float v = acc[i][j] + bsv;
      if (act) v = fmaxf(v, 0.0f) + log1pf(expf(-fabsf(v)));
      out[(size_t)(bt + bi + i) * 128 + colOff + oj + j] = v;
    }
  }
}

// ---------------------------------------------------------------------------
// k4 (MFMA v2): grid (B/32, 64 d), block 256 (4 waves), 3 blocks/CU (53 KB).
// Per block: rows bt..bt+32, one d. As = (d1 o W1[:,d]) full-K resident
// (32x520 bf16). Loop 4 h-tiles of 128 (wave w owns cols w*32..+32, nt=2),
// inner 8 kc of 64 staging Bt (128x72 bf16) from W2bf (pure copy).
// Epilogue folds E = (1-Ybf^2)*W3[d,:] per h-tile into jp registers.
// ---------------------------------------------------------------------------
__global__ __launch_bounds__(256) void k4_mfma(
    const bf16* __restrict__ Xbf, const bf16* __restrict__ Ybf,
    const float* __restrict__ W1, const bf16* __restrict__ W2bf,
    const float* __restrict__ W3, const float* __restrict__ states,
    float* __restrict__ out) {
  __shared__ __align__(16) bf16 As[32 * 520];    // 33280 B
  __shared__ __align__(16) bf16 Bt[128 * 72];    // 18432 B
  __shared__ __align__(16) float w1c[512];       //  2048 B
  __shared__ float red[4 * 32];                  //   512 B

  const int bt = blockIdx.x * 32;
  const int d = blockIdx.y;
  const int t = threadIdx.x;
  const int lane = t & 63;
  const int w = t >> 6;        // wave 0..3
  const int c = lane & 15;     // col lane
  const int q = lane >> 4;     // quad

  // stage W1 column d
  w1c[t] = W1[(size_t)t * DD + d];
  w1c[t + 256] = W1[(size_t)(t + 256) * DD + d];
  __syncthreads();

  // build As[row][k] = bf16((1 - x^2) * w1c[k]), row stride 520
#pragma unroll
  for (int i = 0; i < 8; ++i) {
    int u = t + i * 256;              // 2048 units of 8 elems
    int row = u >> 6, kb = (u & 63) * 8;
    uint4 xraw = *(const uint4*)(Xbf + (size_t)(bt + row) * HH + kb);
    const unsigned short* xs = (const unsigned short*)&xraw;
    float4 wa = *(const float4*)(w1c + kb);
    float4 wb = *(const float4*)(w1c + kb + 4);
    float wv[8] = {wa.x, wa.y, wa.z, wa.w, wb.x, wb.y, wb.z, wb.w};
    bf16 o[8];
#pragma unroll
    for (int j = 0; j < 8; ++j) {
      float x = u16tof(xs[j]);
      o[j] = __float2bfloat16((1.0f - x * x) * wv[j]);
    }
    *(uint4*)(As + row * 520 + kb) = *(const uint4*)o;
  }

  float jp[2][4];
#pragma unroll
  for (int i = 0; i < 2; ++i)
#pragma unroll
    for (int r = 0; r < 4; ++r) jp[i][r] = 0.f;

  for (int ht = 0; ht < 4; ++ht) {
    const int hbase = ht * 128;
    f32x4 acc[2][2] = {{f32x4{0,0,0,0}, f32x4{0,0,0,0}},
                       {f32x4{0,0,0,0}, f32x4{0,0,0,0}}};
    for (int kc = 0; kc < 8; ++kc) {
      __syncthreads();   // previous Bt readers done (also fences As build once)
      // stage Bt: 128 h-rows x 64 k, pure bf16 copy
#pragma unroll
      for (int i = 0; i < 4; ++i) {
        int u = t + i * 256;          // 1024 units of 8 elems
        int hr = u >> 3, kb = (u & 7) * 8;
        uint4 v = *(const uint4*)(W2bf + (size_t)(hbase + hr) * HH + kc * 64 + kb);
        *(uint4*)(Bt + hr * 72 + kb) = v;
      }
      __syncthreads();
#pragma unroll
      for (int s = 0; s < 2; ++s) {
        bf16x8 bfrag[2], afrag[2];
#pragma unroll
        for (int nt = 0; nt < 2; ++nt)
          bfrag[nt] = __builtin_bit_cast(bf16x8,
              *(const uint4*)(Bt + (w * 32 + nt * 16 + c) * 72 + s * 32 + q * 8));
#pragma unroll
        for (int mt = 0; mt < 2; ++mt)
          afrag[mt] = __builtin_bit_cast(bf16x8,
              *(const uint4*)(As + (mt * 16 + c) * 520 + kc * 64 + s * 32 + q * 8));
#pragma unroll
        for (int mt = 0; mt < 2; ++mt)
#pragma unroll
          for (int nt = 0; nt < 2; ++nt)
            acc[mt][nt] = __builtin_amdgcn_mfma_f32_16x16x32_bf16(
                afrag[mt], bfrag[nt], acc[mt][nt], 0, 0, 0);
      }
    }
    // epilogue: jp += acc * (1 - y^2) * W3[d, col]
#pragma unroll
    for (int mt = 0; mt < 2; ++mt)
#pragma unroll
      for (int nt = 0; nt < 2; ++nt) {
        int col = hbase + w * 32 + nt * 16 + c;
        float w3v = W3[(size_t)d * HH + col];
#pragma unroll
        for (int r = 0; r < 4; ++r) {
          int row = mt * 16 + q * 4 + r;
          float y = bf2f(Ybf[(size_t)(bt + row) * HH + col]);
          jp[mt][r] += acc[mt][nt][r] * (1.0f - y * y) * w3v;
        }
      }
  }

  // reduce across the 16 col-lanes (keeps q), then across waves via LDS
#pragma unroll
  for (int mt = 0; mt < 2; ++mt)
#pragma unroll
    for (int r = 0; r < 4; ++r) {
      float v = jp[mt][r];
      v += __shfl_xor(v, 1);
      v += __shfl_xor(v, 2);
      v += __shfl_xor(v, 4);
      v += __shfl_xor(v, 8);
      jp[mt][r] = v;
    }
  if (c == 0) {
#pragma unroll
    for (int mt = 0; mt < 2; ++mt)
#pragma unroll
      for (int r = 0; r < 4; ++r)
        red[w * 32 + mt * 16 + q * 4 + r] = jp[mt][r];
  }
  __syncthreads();
  if (t < 32) {
    float J = red[t] + red[32 + t] + red[64 + t] + red[96 + t];
    int bg = bt + t;
    float sig = states[(size_t)bg * 128 + 64 + d];
    float qd = out[(size_t)bg * 128 + 64 + d];
    out[(size_t)bg * 128 + 64 + d] = 2.0f * J * sig + qd;
  }
}

extern "C" void kernel_launch(void* const* d_in, const int* in_sizes, int n_in,
                              void* d_out, int out_size, void* d_ws, size_t ws_size,
                              hipStream_t stream) {
  // inputs: 0:t 1:states 2:W1 3:b1 4:W2 5:b2 6:W3 7:b3 8:V1 9:c1 10:V2 11:c2 12:V3 13:c3
  const float* states = (const float*)d_in[1];
  const float* W1 = (const float*)d_in[2];
  const float* b1 = (const float*)d_in[3];
  const float* W2 = (const float*)d_in[4];
  const float* b2 = (const float*)d_in[5];
  const float* W3 = (const float*)d_in[6];
  const float* b3 = (const float*)d_in[7];
  const float* V1 = (const float*)d_in[8];
  const float* c1 = (const float*)d_in[9];
  const float* V2 = (const float*)d_in[10];
  const float* c2 = (const float*)d_in[11];
  const float* V3 = (const float*)d_in[12];
  const float* c3 = (const float*)d_in[13];
  float* out = (float*)d_out;

  bf16* Xbf = (bf16*)d_ws;                       // B*H bf16 (4 MB)
  bf16* Ybf = Xbf + (size_t)BB * HH;             // B*H bf16 (4 MB)
  bf16* W2bf = Ybf + (size_t)BB * HH;            // H*H bf16 (0.5 MB)

  w2cvt<<<dim3(256), 256, 0, stream>>>(W2, W2bf);
  // Q path; stash Q_diag (softplus, f32) into out[:, 64:]
  k1_stage1<<<dim3(64, 8), 256, 0, stream>>>(states, V1, c1, Xbf);     // g1
  k2_stage2<<<dim3(64, 8), 256, 0, stream>>>(Xbf, V2, c2, Ybf);        // g2
  k3_stage3<<<dim3(64), 256, 0, stream>>>(Ybf, V3, c3, out, 64, 1);    // Qd
  // h path
  k1_stage1<<<dim3(64, 8), 256, 0, stream>>>(states, W1, b1, Xbf);     // h1
  k2_stage2<<<dim3(64, 8), 256, 0, stream>>>(Xbf, W2, b2, Ybf);        // h2
  k3_stage3<<<dim3(64), 256, 0, stream>>>(Ybf, W3, b3, out, 0, 0);     // mu
  // J_diag + final sigma_drift
  k4_mfma<<<dim3(128, 64), 256, 0, stream>>>(Xbf, Ybf, W1, W2bf, W3, states, out);
}